// Round 4
// baseline (1355.246 us; speedup 1.0000x reference)
//
#include <hip/hip_runtime.h>
#include <hip/hip_bf16.h>

// 2-layer tanh RNN. B=256, T=1024, H=128, V=96. x int32; float tensors
// runtime-detected fp32 vs bf16.
// d_in: 0:x 1:emb 2:W_ih0 3:W_hh0 4:b_ih0 5:b_hh0 6:W_ih1 7:W_hh1 8:b_ih1
//       9:b_hh1 10:fc_W 11:fc_b
// d_out: out[B*T,96] ++ hidden[2,B,128]
//
// R4: 4 waves x 32 cols (halves LDS frag traffic: each wave reads full h0+h1
// once, amortized over 2 N-tiles). embp gather stride 130 halves = 65 words
// (odd) -> per-lane random-row gather spreads over all 32 banks (b32 reads).
// Same single-barrier software pipeline as R3:
//   phase tt: h0(tt) = tanh(ep(tt) + Whh0.h0(tt-1))
//             h1(tt-1) = tanh(b1 + Wih1.h0(tt-1) + Whh1.h1(tt-2))
//             out(tt-2) = fcb + fcW.h1(tt-2)

#define B_SZ 256
#define T_LEN 1024
#define HD 128
#define VC 96
#define OUT_MAIN (B_SZ * T_LEN * VC)
#define HID_OFF OUT_MAIN

#define NB 16              // batches per block
#define NBLK (B_SZ / NB)   // 16 blocks
#define NT 256             // threads = 4 waves
#define EPH 130            // embp row stride (halves) = 65 words (odd: bank-spread)
#define HCH 136            // h chunk stride (halves): conflict-free b128 frags

typedef _Float16 h8v __attribute__((ext_vector_type(8)));
typedef _Float16 h4v __attribute__((ext_vector_type(4)));
typedef _Float16 h2v __attribute__((ext_vector_type(2)));
typedef float f4v __attribute__((ext_vector_type(4)));
typedef unsigned short us4v __attribute__((ext_vector_type(4)));

#define MM(A, Bf, C) __builtin_amdgcn_mfma_f32_16x16x32_f16(A, Bf, C, 0, 0, 0)

// LDS-only barrier: drain LDS ops, never vmcnt (output stores stay in flight).
#define BARRIER()                                          \
  do {                                                     \
    asm volatile("s_waitcnt lgkmcnt(0)" ::: "memory");     \
    __builtin_amdgcn_s_barrier();                          \
    asm volatile("" ::: "memory");                         \
  } while (0)

__device__ __forceinline__ float bf2f(__hip_bfloat16 v) { return __bfloat162float(v); }

__device__ __forceinline__ bool detect_f32(const void* emb) {
  const unsigned short* u = (const unsigned short*)emb;
  int hits = 0;
#pragma unroll
  for (int i = 0; i < 128; ++i) hits += (((u[i] >> 7) & 0xFF) >= 127);
  return hits > 2;
}

__device__ __forceinline__ float ldw(const void* p, int i, bool f32) {
  return f32 ? ((const float*)p)[i] : bf2f(((const __hip_bfloat16*)p)[i]);
}

// tanh(x) = 1 - 2/(e^{2x}+1). Branch/NaN-free; saturates correctly.
__device__ __forceinline__ float tanh_fast(float x) {
  float e = __expf(x + x);
  return 1.0f - __fdividef(2.0f, e + 1.0f);
}

// bf16 RNE round to bits (bounded values).
__device__ __forceinline__ unsigned short f2bfbits(float x) {
  unsigned u = __float_as_uint(x);
  unsigned r = (u + 0x7fffu + ((u >> 16) & 1u)) >> 16;
  return (unsigned short)r;
}

__global__ __launch_bounds__(128) void embp_kernel(
    const void* __restrict__ emb, const void* __restrict__ Wih0,
    const void* __restrict__ bih0, const void* __restrict__ bhh0,
    float* __restrict__ embp) {
  const bool f32 = detect_f32(emb);
  __shared__ float ev[HD];
  const int v = blockIdx.x, r = threadIdx.x;
  ev[r] = ldw(emb, v * HD + r, f32);
  __syncthreads();
  float acc = ldw(bih0, r, f32) + ldw(bhh0, r, f32);
#pragma unroll 8
  for (int j = 0; j < HD; ++j) acc += ldw(Wih0, r * HD + j, f32) * ev[j];
  embp[v * HD + r] = acc;
}

// LDS h layout: (batch m, hidden c) at chunk (c>>3)*HCH + m*8 + (c&7).
// Frag read (lane lm=m, lg, K-tile kt): b128 at (kt*4+lg)*HCH + lm*8.
// Write (wave w, tile nt): h4v at (4w+2nt+(lg>>1))*HCH + lm*8 + 4(lg&1).
template <bool USE_WS>
__global__ __launch_bounds__(NT, 1) void rnn_mfma(
    const int* __restrict__ x,
    const float* __restrict__ embp_g,
    const void* __restrict__ emb,
    const void* __restrict__ Wih0,
    const void* __restrict__ bih0,
    const void* __restrict__ bhh0,
    const void* __restrict__ Whh0,
    const void* __restrict__ Wih1,
    const void* __restrict__ Whh1,
    const void* __restrict__ bih1,
    const void* __restrict__ bhh1,
    const void* __restrict__ fcW,
    const void* __restrict__ fcb_g,
    void* __restrict__ out) {
  __shared__ __align__(16) _Float16 embp16[VC * EPH];   // 24960 B
  __shared__ __align__(16) _Float16 hb0[2][16 * HCH];   // 8704 B (double-buf)
  __shared__ __align__(16) _Float16 hb1[2][16 * HCH];   // 8704 B
  __shared__ __align__(16) unsigned char xb8[T_LEN * NB];  // 16384 B  [t*16+m]

  const int tid = threadIdx.x;
  const int lane = tid & 63;
  const int w = tid >> 6;    // wave 0..3: owns hidden cols 32w..32w+31
  const int lm = lane & 15;  // batch (B-frag col / D col)
  const int lg = lane >> 4;  // k-subchunk / D row group
  const bool f32 = detect_f32(emb);
  const int bbase = blockIdx.x * NB;

  // ---- stage token bytes: xb8[t*16+m] ----
  for (int i = tid; i < NB * T_LEN; i += NT) {
    const int m = i >> 10, t = i & (T_LEN - 1);
    xb8[t * 16 + m] = (unsigned char)x[(bbase + m) * T_LEN + t];
  }

  // ---- stage embp as fp16 (stride EPH=130 halves = 65 words, odd) ----
  if constexpr (USE_WS) {
    const float2* src = (const float2*)embp_g;
    for (int i = tid; i < VC * 64; i += NT) {  // float-pairs
      const int v = i >> 6, j = i & 63;
      const float2 f = src[i];
      h2v p; p[0] = (_Float16)f.x; p[1] = (_Float16)f.y;
      ((h2v*)embp16)[v * (EPH / 2) + j] = p;
    }
  } else {
    const int r = tid & 127, vg = tid >> 7;  // vg 0..1
    const float bsum = ldw(bih0, r, f32) + ldw(bhh0, r, f32);
    for (int vi = 0; vi < 48; ++vi) {
      const int v = vg * 48 + vi;
      float acc = bsum;
#pragma unroll 8
      for (int k = 0; k < HD; ++k)
        acc += ldw(Wih0, r * HD + k, f32) * ldw(emb, v * HD + k, f32);
      embp16[v * EPH + r] = (_Float16)acc;
    }
  }

  // ---- zero both parities of h buffers (h(-1)=h(-2)=0) ----
  for (int i = tid; i < 16 * HCH; i += NT) {
    ((unsigned*)hb0)[i] = 0u;
    ((unsigned*)hb1)[i] = 0u;
  }

  // ---- FC tile assignment: 6 tiles over 4 waves = {0,1},{2,3},{4},{5} ----
  const bool has2 = (w < 2);
  const int fA = (w < 2) ? 2 * w : (w + 2);      // 0,2,4,5
  const int fB = has2 ? (2 * w + 1) : fA;        // 1,3,(dup),(dup)

  // ---- weight A-frags (fp16): 2 N-tiles per wave ----
  // recurrence row n = 32w + 16nt + lm; FC row = 16*f + lm; k = kt*32+lg*8+j
  h8v w0f[2][4], wif[2][4], whf[2][4], wff[2][4];
#pragma unroll
  for (int nt = 0; nt < 2; ++nt) {
    const int n = 32 * w + 16 * nt + lm;
    const int nf = 16 * (nt ? fB : fA) + lm;
#pragma unroll
    for (int kt = 0; kt < 4; ++kt)
#pragma unroll
      for (int j = 0; j < 8; ++j) {
        const int k = kt * 32 + lg * 8 + j;
        w0f[nt][kt][j] = (_Float16)ldw(Whh0, n * HD + k, f32);
        wif[nt][kt][j] = (_Float16)ldw(Wih1, n * HD + k, f32);
        whf[nt][kt][j] = (_Float16)ldw(Whh1, n * HD + k, f32);
        wff[nt][kt][j] = (_Float16)ldw(fcW, nf * HD + k, f32);
      }
  }
  // biases: acc elem r <-> col 32w+16nt+4lg+r (recurrence), 16f+4lg+r (FC)
  f4v b1v[2], fcv[2];
#pragma unroll
  for (int nt = 0; nt < 2; ++nt)
#pragma unroll
    for (int r = 0; r < 4; ++r) {
      const int c = 32 * w + 16 * nt + 4 * lg + r;
      b1v[nt][r] = ldw(bih1, c, f32) + ldw(bhh1, c, f32);
      fcv[nt][r] = ldw(fcb_g, 16 * (nt ? fB : fA) + 4 * lg + r, f32);
    }

  const int rdb = lg * HCH + lm * 8;  // frag read base; + kt*4*HCH
  const int wofs0 = (4 * w + (lg >> 1)) * HCH + lm * 8 + 4 * (lg & 1);
  const int wofs1 = wofs0 + 2 * HCH;
  const int g0 = 32 * w + 4 * lg;     // ep gather col base (tile0); +16 tile1

  __syncthreads();  // staging visible

  // ---- prologue: ep(0) gather, xid(1) ----
  h2v ep0, ep1, ep2, ep3;
  int xcur;
  {
    const int x0 = xb8[0 * 16 + lm];
    xcur = xb8[1 * 16 + lm];
    const int gb = x0 * EPH + g0;
    ep0 = *(const h2v*)&embp16[gb];
    ep1 = *(const h2v*)&embp16[gb + 2];
    ep2 = *(const h2v*)&embp16[gb + 16];
    ep3 = *(const h2v*)&embp16[gb + 18];
  }

  float* outf = (float*)out;
  unsigned short* outu = (unsigned short*)out;

#pragma unroll 1
  for (int tt = 0; tt < T_LEN + 2; ++tt) {
    const int q = (tt & 1) ^ 1, p = tt & 1;
    // ---- issue all LDS reads up front ----
    h8v h0f[4], h1f[4];
#pragma unroll
    for (int kt = 0; kt < 4; ++kt) {
      h0f[kt] = *(const h8v*)&hb0[q][rdb + kt * 4 * HCH];
      h1f[kt] = *(const h8v*)&hb1[q][rdb + kt * 4 * HCH];
    }
    const int t2 = (tt + 2 < T_LEN) ? tt + 2 : T_LEN - 1;
    const int xnext = xb8[t2 * 16 + lm];  // xid(tt+2)
    const int gb = xcur * EPH + g0;       // ep(tt+1), bank = xid + const
    const h2v en0 = *(const h2v*)&embp16[gb];
    const h2v en1 = *(const h2v*)&embp16[gb + 2];
    const h2v en2 = *(const h2v*)&embp16[gb + 16];
    const h2v en3 = *(const h2v*)&embp16[gb + 18];

    // ---- MFMA groups (16 independent accumulator chains) ----
    const f4v z = {0.f, 0.f, 0.f, 0.f};
    f4v a00 = {(float)ep0[0], (float)ep0[1], (float)ep1[0], (float)ep1[1]};
    f4v a01 = {(float)ep2[0], (float)ep2[1], (float)ep3[0], (float)ep3[1]};
    f4v a00b = z, a01b = z;
    f4v b10 = b1v[0], b11 = b1v[1], b10b = z, b11b = z;
    f4v c10 = z, c11 = z, c10b = z, c11b = z;
    // h0f consumers (Whh0, Wih1)
    a00  = MM(w0f[0][0], h0f[0], a00);   a01  = MM(w0f[1][0], h0f[0], a01);
    b10  = MM(wif[0][0], h0f[0], b10);   b11  = MM(wif[1][0], h0f[0], b11);
    a00  = MM(w0f[0][1], h0f[1], a00);   a01  = MM(w0f[1][1], h0f[1], a01);
    b10  = MM(wif[0][1], h0f[1], b10);   b11  = MM(wif[1][1], h0f[1], b11);
    a00b = MM(w0f[0][2], h0f[2], a00b);  a01b = MM(w0f[1][2], h0f[2], a01b);
    b10b = MM(wif[0][2], h0f[2], b10b);  b11b = MM(wif[1][2], h0f[2], b11b);
    a00b = MM(w0f[0][3], h0f[3], a00b);  a01b = MM(w0f[1][3], h0f[3], a01b);
    b10b = MM(wif[0][3], h0f[3], b10b);  b11b = MM(wif[1][3], h0f[3], b11b);
    // h1f consumers (Whh1)
    c10  = MM(whf[0][0], h1f[0], c10);   c11  = MM(whf[1][0], h1f[0], c11);
    c10  = MM(whf[0][1], h1f[1], c10);   c11  = MM(whf[1][1], h1f[1], c11);
    c10b = MM(whf[0][2], h1f[2], c10b);  c11b = MM(whf[1][2], h1f[2], c11b);
    c10b = MM(whf[0][3], h1f[3], c10b);  c11b = MM(whf[1][3], h1f[3], c11b);
    // FC (h1f)
    f4v f0 = fcv[0], f0b = z, f1 = fcv[1], f1b = z;
    f0  = MM(wff[0][0], h1f[0], f0);     f0  = MM(wff[0][1], h1f[1], f0);
    f0b = MM(wff[0][2], h1f[2], f0b);    f0b = MM(wff[0][3], h1f[3], f0b);
    if (has2) {
      f1  = MM(wff[1][0], h1f[0], f1);   f1  = MM(wff[1][1], h1f[1], f1);
      f1b = MM(wff[1][2], h1f[2], f1b);  f1b = MM(wff[1][3], h1f[3], f1b);
    }

    // ---- h0(tt) -> hb0[p] ----
    if (tt < T_LEN) {
      const f4v s0 = a00 + a00b, s1 = a01 + a01b;
      h4v o0, o1;
#pragma unroll
      for (int r = 0; r < 4; ++r) {
        o0[r] = (_Float16)tanh_fast(s0[r]);
        o1[r] = (_Float16)tanh_fast(s1[r]);
      }
      *(h4v*)&hb0[p][wofs0] = o0;
      *(h4v*)&hb0[p][wofs1] = o1;
    }
    // ---- h1(tt-1) -> hb1[p] ----
    if (tt >= 1 && tt <= T_LEN) {
      const f4v s0 = (b10 + b10b) + (c10 + c10b);
      const f4v s1 = (b11 + b11b) + (c11 + c11b);
      h4v o0, o1;
#pragma unroll
      for (int r = 0; r < 4; ++r) {
        o0[r] = (_Float16)tanh_fast(s0[r]);
        o1[r] = (_Float16)tanh_fast(s1[r]);
      }
      *(h4v*)&hb1[p][wofs0] = o0;
      *(h4v*)&hb1[p][wofs1] = o1;
    }
    // ---- out(tt-2) store (never awaited in-loop) ----
    if (tt >= 2) {
      const long rowb = ((long)(bbase + lm) * T_LEN + (tt - 2)) * VC;
      const f4v sA = f0 + f0b;
      const int vA = 16 * fA + 4 * lg;
      if (f32) {
        *(f4v*)&outf[rowb + vA] = sA;
      } else {
        us4v u;
#pragma unroll
        for (int r = 0; r < 4; ++r) u[r] = f2bfbits(sA[r]);
        *(us4v*)&outu[rowb + vA] = u;
      }
      if (has2) {
        const f4v sB = f1 + f1b;
        const int vB = 16 * fB + 4 * lg;
        if (f32) {
          *(f4v*)&outf[rowb + vB] = sB;
        } else {
          us4v u;
#pragma unroll
          for (int r = 0; r < 4; ++r) u[r] = f2bfbits(sB[r]);
          *(us4v*)&outu[rowb + vB] = u;
        }
      }
    }

    BARRIER();
    ep0 = en0; ep1 = en1; ep2 = en2; ep3 = en3;
    xcur = xnext;
  }

  // ---- final hidden: h0(T-1) in hb0[1], h1(T-1) in hb1[0] ----
  {
    const int m = tid >> 4, ch = tid & 15;
    const h8v v0 = *(const h8v*)&hb0[(T_LEN - 1) & 1][ch * HCH + m * 8];
    const h8v v1 = *(const h8v*)&hb1[T_LEN & 1][ch * HCH + m * 8];
    const long i0 = HID_OFF + (long)(bbase + m) * HD + ch * 8;
    const long i1 = i0 + (long)B_SZ * HD;
    if (f32) {
#pragma unroll
      for (int j = 0; j < 8; ++j) {
        outf[i0 + j] = (float)v0[j];
        outf[i1 + j] = (float)v1[j];
      }
    } else {
#pragma unroll
      for (int j = 0; j < 8; ++j) {
        outu[i0 + j] = f2bfbits((float)v0[j]);
        outu[i1 + j] = f2bfbits((float)v1[j]);
      }
    }
  }
}

extern "C" void kernel_launch(void* const* d_in, const int* in_sizes, int n_in,
                              void* d_out, int out_size, void* d_ws, size_t ws_size,
                              hipStream_t stream) {
  const int* x = (const int*)d_in[0];
  const void* emb = d_in[1];
  const void* Wih0 = d_in[2];
  const void* Whh0 = d_in[3];
  const void* bih0 = d_in[4];
  const void* bhh0 = d_in[5];
  const void* Wih1 = d_in[6];
  const void* Whh1 = d_in[7];
  const void* bih1 = d_in[8];
  const void* bhh1 = d_in[9];
  const void* fcW = d_in[10];
  const void* fcb = d_in[11];

  const size_t need = (size_t)VC * HD * sizeof(float);
  if (d_ws != nullptr && ws_size >= need) {
    float* embp = (float*)d_ws;
    embp_kernel<<<VC, HD, 0, stream>>>(emb, Wih0, bih0, bhh0, embp);
    rnn_mfma<true><<<NBLK, NT, 0, stream>>>(x, embp, emb, Wih0, bih0, bhh0,
                                            Whh0, Wih1, Whh1, bih1, bhh1,
                                            fcW, fcb, d_out);
  } else {
    rnn_mfma<false><<<NBLK, NT, 0, stream>>>(x, nullptr, emb, Wih0, bih0, bhh0,
                                             Whh0, Wih1, Whh1, bih1, bhh1,
                                             fcW, fcb, d_out);
  }
}

// Round 5
// 898.000 us; speedup vs baseline: 1.5092x; 1.5092x over previous
//
#include <hip/hip_runtime.h>
#include <hip/hip_bf16.h>

// 2-layer tanh RNN. B=256, T=1024, H=128, V=96. x int32; float tensors
// runtime-detected fp32 vs bf16.
// d_in: 0:x 1:emb 2:W_ih0 3:W_hh0 4:b_ih0 5:b_hh0 6:W_ih1 7:W_hh1 8:b_ih1
//       9:b_hh1 10:fc_W 11:fc_b
// d_out: out[B*T,96] ++ hidden[2,B,128]
//
// R5: R3's 8-wave single-barrier pipeline (best measured) + VALU cuts:
//  - MFMA C-operands seeded with ep/bias/fcb, full 4-chains (no zero-init movs,
//    no combine adds; h1 = one 8-chain seeded with b1)
//  - tanh = 3 VALU + 2 trans (exp2 + rcp + fma)
//  - FC bf16 store via v_cvt_pk_bf16_f32 (2 instr / 4 values)
//  - ep gather = single ds_read_b64 (EPH=132, 8B-aligned)
//  - peeled prologue/epilogue, 2x-unrolled steady loop (compile-time parity,
//    no in-loop branches), incremental output pointer
// Pipeline phase tt: h0(tt) = tanh(ep(tt) + Whh0.h0(tt-1))
//                    h1(tt-1) = tanh(b1 + Wih1.h0(tt-1) + Whh1.h1(tt-2))
//                    out(tt-2) = fcb + fcW.h1(tt-2)

#define B_SZ 256
#define T_LEN 1024
#define HD 128
#define VC 96
#define OUT_MAIN (B_SZ * T_LEN * VC)
#define HID_OFF OUT_MAIN

#define NB 16              // batches per block
#define NBLK (B_SZ / NB)   // 16 blocks
#define NT 512             // threads = 8 waves
#define EPH 132            // embp row stride (halves): mult of 4 -> b64 gather
#define HCH 136            // h chunk stride (halves): b128 frag reads

typedef _Float16 h8v __attribute__((ext_vector_type(8)));
typedef _Float16 h4v __attribute__((ext_vector_type(4)));
typedef _Float16 h2v __attribute__((ext_vector_type(2)));
typedef float f4v __attribute__((ext_vector_type(4)));

#define MM(A, Bf, C) __builtin_amdgcn_mfma_f32_16x16x32_f16(A, Bf, C, 0, 0, 0)

// LDS-only barrier: drain LDS ops, never vmcnt (output stores stay in flight).
#define BARRIER()                                          \
  do {                                                     \
    asm volatile("s_waitcnt lgkmcnt(0)" ::: "memory");     \
    __builtin_amdgcn_s_barrier();                          \
    asm volatile("" ::: "memory");                         \
  } while (0)

__device__ __forceinline__ float bf2f(__hip_bfloat16 v) { return __bfloat162float(v); }

__device__ __forceinline__ bool detect_f32(const void* emb) {
  const unsigned short* u = (const unsigned short*)emb;
  int hits = 0;
#pragma unroll
  for (int i = 0; i < 128; ++i) hits += (((u[i] >> 7) & 0xFF) >= 127);
  return hits > 2;
}

__device__ __forceinline__ float ldw(const void* p, int i, bool f32) {
  return f32 ? ((const float*)p)[i] : bf2f(((const __hip_bfloat16*)p)[i]);
}

// tanh(x) = 1 - 2/(e^{2x}+1), e^{2x} = 2^(x*2log2e). 3 VALU + 2 trans.
// Saturates correctly: x->+inf: e->inf, rcp->0, y->1; x->-inf: e->0, y->-1.
__device__ __forceinline__ float tanh_fast(float x) {
  const float e = exp2f(x * 2.885390082f);
  const float r = __builtin_amdgcn_rcpf(e + 1.0f);
  return fmaf(-2.0f, r, 1.0f);
}

// bf16 RNE round to bits (bounded values) — used in cold epilogue only.
__device__ __forceinline__ unsigned short f2bfbits(float x) {
  unsigned u = __float_as_uint(x);
  unsigned r = (u + 0x7fffu + ((u >> 16) & 1u)) >> 16;
  return (unsigned short)r;
}

// packed f32x2 -> bf16x2 (hot path, 1 instr)
__device__ __forceinline__ unsigned cvt_pk_bf16(float lo, float hi) {
  unsigned r;
  asm("v_cvt_pk_bf16_f32 %0, %1, %2" : "=v"(r) : "v"(lo), "v"(hi));
  return r;
}

__global__ __launch_bounds__(128) void embp_kernel(
    const void* __restrict__ emb, const void* __restrict__ Wih0,
    const void* __restrict__ bih0, const void* __restrict__ bhh0,
    float* __restrict__ embp) {
  const bool f32 = detect_f32(emb);
  __shared__ float ev[HD];
  const int v = blockIdx.x, r = threadIdx.x;
  ev[r] = ldw(emb, v * HD + r, f32);
  __syncthreads();
  float acc = ldw(bih0, r, f32) + ldw(bhh0, r, f32);
#pragma unroll 8
  for (int j = 0; j < HD; ++j) acc += ldw(Wih0, r * HD + j, f32) * ev[j];
  embp[v * HD + r] = acc;
}

// LDS h layout: (batch m, hidden c) at chunk (c>>3)*HCH + m*8 + (c&7).
// Frag read (lane lm=m, lg, K-tile kt): b128 at (kt*4+lg)*HCH + lm*8.
// Write (wave w owns cols 16w..16w+15): h4v at (2w+(lg>>1))*HCH + lm*8 + 4(lg&1).
template <bool USE_WS>
__global__ __launch_bounds__(NT, 2) void rnn_mfma(
    const int* __restrict__ x,
    const float* __restrict__ embp_g,
    const void* __restrict__ emb,
    const void* __restrict__ Wih0,
    const void* __restrict__ bih0,
    const void* __restrict__ bhh0,
    const void* __restrict__ Whh0,
    const void* __restrict__ Wih1,
    const void* __restrict__ Whh1,
    const void* __restrict__ bih1,
    const void* __restrict__ bhh1,
    const void* __restrict__ fcW,
    const void* __restrict__ fcb_g,
    void* __restrict__ out) {
  __shared__ __align__(16) _Float16 embp16[VC * EPH];        // 25344 B
  __shared__ __align__(16) _Float16 hb0[2][16 * HCH];        // 8704 B
  __shared__ __align__(16) _Float16 hb1[2][16 * HCH];        // 8704 B
  __shared__ __align__(16) unsigned char xb8[(T_LEN + 2) * NB];  // 16416 B

  const int tid = threadIdx.x;
  const int lane = tid & 63;
  const int w = tid >> 6;    // wave 0..7: owns hidden/vocab rows 16w..16w+15
  const int lm = lane & 15;  // batch (B-frag col / D col)
  const int lg = lane >> 4;  // k-subchunk / D row group
  const bool f32 = detect_f32(emb);
  const int bbase = blockIdx.x * NB;

  // ---- stage token bytes: xb8[t*16+m], padded 2 steps ----
  for (int i = tid; i < NB * T_LEN; i += NT) {
    const int m = i >> 10, t = i & (T_LEN - 1);
    xb8[t * 16 + m] = (unsigned char)x[(bbase + m) * T_LEN + t];
  }
  if (tid < 2 * NB) {
    const int t = T_LEN + (tid >> 4), m = tid & 15;
    xb8[t * 16 + m] = (unsigned char)x[(bbase + m) * T_LEN + (T_LEN - 1)];
  }

  // ---- stage embp as fp16 (stride EPH=132 halves) ----
  if constexpr (USE_WS) {
    const float2* src = (const float2*)embp_g;
    for (int i = tid; i < VC * 64; i += NT) {  // float-pairs
      const int v = i >> 6, j = i & 63;
      const float2 f = src[i];
      h2v p; p[0] = (_Float16)f.x; p[1] = (_Float16)f.y;
      ((h2v*)embp16)[v * (EPH / 2) + j] = p;
    }
  } else {
    const int r = tid & 127, vg = tid >> 7;  // vg 0..3
    const float bsum = ldw(bih0, r, f32) + ldw(bhh0, r, f32);
    for (int vi = 0; vi < 24; ++vi) {
      const int v = vg * 24 + vi;
      float acc = bsum;
#pragma unroll 8
      for (int k = 0; k < HD; ++k)
        acc += ldw(Wih0, r * HD + k, f32) * ldw(emb, v * HD + k, f32);
      embp16[v * EPH + r] = (_Float16)acc;
    }
  }

  // ---- zero both parities of h buffers (h(-1)=h(-2)=0) ----
  for (int i = tid; i < 16 * HCH; i += NT) {
    ((unsigned*)hb0)[i] = 0u;
    ((unsigned*)hb1)[i] = 0u;
  }

  const bool fcact = (w < 6);  // FC rows 0..95 on waves 0..5

  // ---- weight A-frags (fp16): row 16w+lm, k = kt*32 + lg*8 + j ----
  h8v w0[4], wi[4], wh[4], wf[4];
  {
    const int n = 16 * w + lm;
#pragma unroll
    for (int kt = 0; kt < 4; ++kt)
#pragma unroll
      for (int j = 0; j < 8; ++j) {
        const int k = kt * 32 + lg * 8 + j;
        w0[kt][j] = (_Float16)ldw(Whh0, n * HD + k, f32);
        wi[kt][j] = (_Float16)ldw(Wih1, n * HD + k, f32);
        wh[kt][j] = (_Float16)ldw(Whh1, n * HD + k, f32);
        wf[kt][j] = (_Float16)(fcact ? ldw(fcW, n * HD + k, f32) : 0.0f);
      }
  }
  // biases: acc elem r <-> row c = 16w + 4lg + r
  f4v b1v, fcv;
#pragma unroll
  for (int r = 0; r < 4; ++r) {
    const int c = 16 * w + 4 * lg + r;
    b1v[r] = ldw(bih1, c, f32) + ldw(bhh1, c, f32);
    fcv[r] = fcact ? ldw(fcb_g, c, f32) : 0.0f;
  }

  const int rdb = lg * HCH + lm * 8;  // frag read base; + kt*4*HCH
  const int wofs = (2 * w + (lg >> 1)) * HCH + lm * 8 + 4 * (lg & 1);
  const int gofs = 16 * w + 4 * lg;   // ep gather col base (lane's own 4 cols)

  __syncthreads();  // staging visible

  // ---- prologue: ep(0), xid(1) ----
  h4v epc;
  int xcur;
  const unsigned char* xbp = &xb8[2 * 16 + lm];  // -> xid(tt+2) stream
  {
    const int x0 = xb8[0 * 16 + lm];
    xcur = xb8[1 * 16 + lm];
    epc = *(const h4v*)&embp16[x0 * EPH + gofs];
  }

  // incremental output pointer (lane's batch row, t=0, col 16w+4lg)
  char* po = (char*)out;
  long ostride = 0;
  if (fcact) {
    const long e0 = (long)(bbase + lm) * T_LEN * VC + 16 * w + 4 * lg;
    po = (char*)out + e0 * (f32 ? 4 : 2);
    ostride = (long)VC * (f32 ? 4 : 2);
  }

// One pipeline phase. Q/P = read/write parity (compile-time), DO_* flags const.
#define STEP(Q, P, DO_H0, DO_H1, DO_OUT)                                       \
  do {                                                                         \
    h8v h0f[4], h1f[4];                                                        \
    if (DO_H0 || DO_H1) {                                                      \
      _Pragma("unroll") for (int kt = 0; kt < 4; ++kt)                         \
          h0f[kt] = *(const h8v*)&hb0[Q][rdb + kt * 4 * HCH];                  \
    }                                                                          \
    _Pragma("unroll") for (int kt = 0; kt < 4; ++kt)                           \
        h1f[kt] = *(const h8v*)&hb1[Q][rdb + kt * 4 * HCH];                    \
    int xnext_ = 0;                                                            \
    h4v epn_ = epc;                                                            \
    if (DO_H0) {                                                               \
      xnext_ = *xbp; xbp += 16;                                                \
      epn_ = *(const h4v*)&embp16[xcur * EPH + gofs];                          \
    }                                                                          \
    if (DO_H0) {                                                               \
      f4v a0 = {(float)epc[0], (float)epc[1], (float)epc[2], (float)epc[3]};   \
      a0 = MM(w0[0], h0f[0], a0); a0 = MM(w0[1], h0f[1], a0);                  \
      a0 = MM(w0[2], h0f[2], a0); a0 = MM(w0[3], h0f[3], a0);                  \
      h4v o;                                                                   \
      _Pragma("unroll") for (int r = 0; r < 4; ++r)                            \
          o[r] = (_Float16)tanh_fast(a0[r]);                                   \
      *(h4v*)&hb0[P][wofs] = o;                                                \
    }                                                                          \
    if (DO_H1) {                                                               \
      f4v a1 = MM(wi[0], h0f[0], b1v);                                         \
      a1 = MM(wi[1], h0f[1], a1); a1 = MM(wi[2], h0f[2], a1);                  \
      a1 = MM(wi[3], h0f[3], a1);                                              \
      a1 = MM(wh[0], h1f[0], a1); a1 = MM(wh[1], h1f[1], a1);                  \
      a1 = MM(wh[2], h1f[2], a1); a1 = MM(wh[3], h1f[3], a1);                  \
      h4v o;                                                                   \
      _Pragma("unroll") for (int r = 0; r < 4; ++r)                            \
          o[r] = (_Float16)tanh_fast(a1[r]);                                   \
      *(h4v*)&hb1[P][wofs] = o;                                                \
    }                                                                          \
    if (DO_OUT && fcact) {                                                     \
      f4v a2 = MM(wf[0], h1f[0], fcv);                                         \
      a2 = MM(wf[1], h1f[1], a2); a2 = MM(wf[2], h1f[2], a2);                  \
      a2 = MM(wf[3], h1f[3], a2);                                              \
      if (f32) {                                                               \
        *(f4v*)po = a2;                                                        \
      } else {                                                                 \
        uint2 u;                                                               \
        u.x = cvt_pk_bf16(a2[0], a2[1]);                                       \
        u.y = cvt_pk_bf16(a2[2], a2[3]);                                       \
        *(uint2*)po = u;                                                       \
      }                                                                        \
      po += ostride;                                                           \
    }                                                                          \
    BARRIER();                                                                 \
    if (DO_H0) { epc = epn_; xcur = xnext_; }                                  \
  } while (0)

  STEP(1, 0, true, false, false);  // tt=0: h0(0)
  STEP(0, 1, true, true, false);   // tt=1: h0(1), h1(0)
#pragma unroll 1
  for (int tt = 2; tt < T_LEN; tt += 2) {
    STEP(1, 0, true, true, true);
    STEP(0, 1, true, true, true);
  }
  STEP(1, 0, false, true, true);   // tt=1024: h1(1023), out(1022)
  STEP(0, 1, false, false, true);  // tt=1025: out(1023)
#undef STEP

  float* outf = (float*)out;
  unsigned short* outu = (unsigned short*)out;

  // ---- final hidden: h0(T-1) in hb0[1], h1(T-1) in hb1[0] ----
  if (tid < 256) {
    const int m = tid >> 4, ch = tid & 15;
    const h8v v0 = *(const h8v*)&hb0[(T_LEN - 1) & 1][ch * HCH + m * 8];
    const h8v v1 = *(const h8v*)&hb1[T_LEN & 1][ch * HCH + m * 8];
    const long i0 = HID_OFF + (long)(bbase + m) * HD + ch * 8;
    const long i1 = i0 + (long)B_SZ * HD;
    if (f32) {
#pragma unroll
      for (int j = 0; j < 8; ++j) {
        outf[i0 + j] = (float)v0[j];
        outf[i1 + j] = (float)v1[j];
      }
    } else {
#pragma unroll
      for (int j = 0; j < 8; ++j) {
        outu[i0 + j] = f2bfbits((float)v0[j]);
        outu[i1 + j] = f2bfbits((float)v1[j]);
      }
    }
  }
}

extern "C" void kernel_launch(void* const* d_in, const int* in_sizes, int n_in,
                              void* d_out, int out_size, void* d_ws, size_t ws_size,
                              hipStream_t stream) {
  const int* x = (const int*)d_in[0];
  const void* emb = d_in[1];
  const void* Wih0 = d_in[2];
  const void* Whh0 = d_in[3];
  const void* bih0 = d_in[4];
  const void* bhh0 = d_in[5];
  const void* Wih1 = d_in[6];
  const void* Whh1 = d_in[7];
  const void* bih1 = d_in[8];
  const void* bhh1 = d_in[9];
  const void* fcW = d_in[10];
  const void* fcb = d_in[11];

  const size_t need = (size_t)VC * HD * sizeof(float);
  if (d_ws != nullptr && ws_size >= need) {
    float* embp = (float*)d_ws;
    embp_kernel<<<VC, HD, 0, stream>>>(emb, Wih0, bih0, bhh0, embp);
    rnn_mfma<true><<<NBLK, NT, 0, stream>>>(x, embp, emb, Wih0, bih0, bhh0,
                                            Whh0, Wih1, Whh1, bih1, bhh1,
                                            fcW, fcb, d_out);
  } else {
    rnn_mfma<false><<<NBLK, NT, 0, stream>>>(x, nullptr, emb, Wih0, bih0, bhh0,
                                             Whh0, Wih1, Whh1, bih1, bhh1,
                                             fcW, fcb, d_out);
  }
}